// Round 1
// baseline (2464.211 us; speedup 1.0000x reference)
//
#include <hip/hip_runtime.h>
#include <math.h>

#define QUEUE 8192
#define BATCH 256
#define NROW  8448        // QUEUE + BATCH
#define DIM   512
#define NCLS  65
#define KNB   10
#define NSPLIT 11
#define SPLITC 768        // 8448 / 11, divisible by BN
#define BM 128
#define BN 128
#define BK 32
#define LP 132            // padded LDS stride (words)

// ---------------- kernel 1: row normalize ----------------
__global__ __launch_bounds__(128) void k_norm(const float* __restrict__ mem,
                                              const float* __restrict__ xq,
                                              float* __restrict__ sn) {
    int row = blockIdx.x;
    const float* src = (row < QUEUE) ? (mem + (size_t)row * DIM)
                                     : (xq + (size_t)(row - QUEUE) * DIM);
    float4 v = reinterpret_cast<const float4*>(src)[threadIdx.x];
    float ss = v.x*v.x + v.y*v.y + v.z*v.z + v.w*v.w;
    #pragma unroll
    for (int o = 32; o > 0; o >>= 1) ss += __shfl_xor(ss, o);
    __shared__ float s2[2];
    if ((threadIdx.x & 63) == 0) s2[threadIdx.x >> 6] = ss;
    __syncthreads();
    float nrm = fmaxf(sqrtf(s2[0] + s2[1]), 1e-12f);
    float4 o4 = make_float4(v.x / nrm, v.y / nrm, v.z / nrm, v.w / nrm);
    reinterpret_cast<float4*>(sn + (size_t)row * DIM)[threadIdx.x] = o4;
}

// ---------------- kernel 2: fused sim GEMM + per-row top-10 (per column split) ----------------
__global__ __launch_bounds__(256) void k_simtopk(const float* __restrict__ sn,
                                                 float* __restrict__ pwv,
                                                 int* __restrict__ pwi) {
    __shared__ float At[BK][LP];        // [k][row]  (transposed)
    __shared__ float Bt[BK][LP];        // [k][col]
    __shared__ float strip[16][LP];     // one 16-row slice of the C tile
    __shared__ float lv[BM][KNB];
    __shared__ int   li[BM][KNB];

    int band  = blockIdx.x / NSPLIT;    // 0..65 (row band)
    int split = blockIdx.x % NSPLIT;    // 0..10 (column split)
    int i0 = band * BM;
    int cbase0 = split * SPLITC;

    int tid  = threadIdx.x;
    int rg   = tid >> 4;                // 0..15 : rows {4rg+i, 64+4rg+i}
    int cg   = tid & 15;                // 0..15 : cols {4cg+j, 64+4cg+j}
    int wave = tid >> 6;
    int lane = tid & 63;

    for (int t = tid; t < BM * KNB; t += 256) {
        (&lv[0][0])[t] = -1e30f; (&li[0][0])[t] = 0;
    }
    __syncthreads();

    for (int chunk = 0; chunk < SPLITC / BN; ++chunk) {   // 6 chunks
        int c0 = cbase0 + chunk * BN;
        float acc[8][8];
        #pragma unroll
        for (int a = 0; a < 8; ++a)
            #pragma unroll
            for (int b = 0; b < 8; ++b) acc[a][b] = 0.f;

        for (int k0 = 0; k0 < DIM; k0 += BK) {
            __syncthreads();
            // stage A^T and B^T (4096 floats each): thread -> (row r, 4 k's)
            {
                int r  = tid >> 3;             // 0..31
                int kq = (tid & 7) << 2;       // 0,4,...,28
                #pragma unroll
                for (int p = 0; p < 4; ++p) {
                    int rr = r + p * 32;
                    float4 va = *reinterpret_cast<const float4*>(sn + (size_t)(i0 + rr) * DIM + k0 + kq);
                    At[kq+0][rr] = va.x; At[kq+1][rr] = va.y; At[kq+2][rr] = va.z; At[kq+3][rr] = va.w;
                    float4 vb = *reinterpret_cast<const float4*>(sn + (size_t)(c0 + rr) * DIM + k0 + kq);
                    Bt[kq+0][rr] = vb.x; Bt[kq+1][rr] = vb.y; Bt[kq+2][rr] = vb.z; Bt[kq+3][rr] = vb.w;
                }
            }
            __syncthreads();
            #pragma unroll 4
            for (int k = 0; k < BK; ++k) {
                float4 a0 = *reinterpret_cast<const float4*>(&At[k][4 * rg]);
                float4 a1 = *reinterpret_cast<const float4*>(&At[k][64 + 4 * rg]);
                float4 b0 = *reinterpret_cast<const float4*>(&Bt[k][4 * cg]);
                float4 b1 = *reinterpret_cast<const float4*>(&Bt[k][64 + 4 * cg]);
                float av[8] = {a0.x,a0.y,a0.z,a0.w,a1.x,a1.y,a1.z,a1.w};
                float bv[8] = {b0.x,b0.y,b0.z,b0.w,b1.x,b1.y,b1.z,b1.w};
                #pragma unroll
                for (int a = 0; a < 8; ++a)
                    #pragma unroll
                    for (int b = 0; b < 8; ++b)
                        acc[a][b] = fmaf(av[a], bv[b], acc[a][b]);
            }
        }

        // top-k update: 8 strips of 16 rows
        #pragma unroll 1
        for (int s = 0; s < 8; ++s) {
            int ri = s >> 2, ii = s & 3;
            __syncthreads();   // previous strip fully consumed
            *reinterpret_cast<float4*>(&strip[rg][4 * cg]) =
                make_float4(acc[s][0], acc[s][1], acc[s][2], acc[s][3]);
            *reinterpret_cast<float4*>(&strip[rg][64 + 4 * cg]) =
                make_float4(acc[s][4], acc[s][5], acc[s][6], acc[s][7]);
            __syncthreads();
            // wave w owns strip rows 4w..4w+3
            for (int q = 0; q < 4; ++q) {
                int srg  = wave * 4 + q;
                int rloc = 64 * ri + 4 * srg + ii;    // local row 0..127
                int grow = i0 + rloc;
                float v0 = strip[srg][lane];
                float v1 = strip[srg][64 + lane];
                int gc0 = c0 + lane, gc1 = c0 + 64 + lane;
                float thr = lv[rloc][KNB - 1];
                unsigned long long m0 = __ballot((v0 > thr) && (gc0 != grow));
                unsigned long long m1 = __ballot((v1 > thr) && (gc1 != grow));
                while (m0 | m1) {
                    float cv; int cidx;
                    if (m0) { int l = __ffsll(m0) - 1; m0 &= m0 - 1; cv = __shfl(v0, l); cidx = c0 + l; }
                    else    { int l = __ffsll(m1) - 1; m1 &= m1 - 1; cv = __shfl(v1, l); cidx = c0 + 64 + l; }
                    thr = lv[rloc][KNB - 1];
                    if (cv > thr && lane == 0) {
                        int p = KNB - 1;
                        while (p > 0 && lv[rloc][p - 1] < cv) {
                            lv[rloc][p] = lv[rloc][p - 1];
                            li[rloc][p] = li[rloc][p - 1];
                            --p;
                        }
                        lv[rloc][p] = cv; li[rloc][p] = cidx;
                    }
                }
            }
        }
    }
    __syncthreads();
    for (int t = tid; t < BM * KNB; t += 256) {
        int r = t / KNB, q = t % KNB;
        size_t o = ((size_t)(i0 + r) * NSPLIT + split) * KNB + q;
        pwv[o] = lv[r][q]; pwi[o] = li[r][q];
    }
}

// ---------------- kernel 3: merge 11 partial top-10 lists per row ----------------
__global__ __launch_bounds__(256) void k_merge(const float* __restrict__ pwv,
                                               const int* __restrict__ pwi,
                                               float* __restrict__ wv,
                                               int* __restrict__ wi) {
    int row = blockIdx.x * 256 + threadIdx.x;
    if (row >= NROW) return;
    float tv[KNB]; int ti[KNB];
    #pragma unroll
    for (int p = 0; p < KNB; ++p) { tv[p] = -1e30f; ti[p] = 0; }
    const float* pv = pwv + (size_t)row * NSPLIT * KNB;
    const int*   pi = pwi + (size_t)row * NSPLIT * KNB;
    for (int s = 0; s < NSPLIT * KNB; ++s) {
        float v = pv[s]; int id = pi[s];
        #pragma unroll
        for (int p = KNB - 1; p >= 1; --p) {
            bool shift = tv[p-1] < v;
            bool ins   = !shift && (tv[p] < v);
            tv[p] = shift ? tv[p-1] : (ins ? v  : tv[p]);
            ti[p] = shift ? ti[p-1] : (ins ? id : ti[p]);
        }
        if (tv[0] < v) { tv[0] = v; ti[0] = id; }
    }
    #pragma unroll
    for (int p = 0; p < KNB; ++p) {
        wv[(size_t)row * KNB + p] = tv[p];
        wi[(size_t)row * KNB + p] = ti[p];
    }
}

// ---------------- kernel 4: GNN pass (FIRST uses one-hot labels implicitly) ----------------
template<int FIRST>
__global__ __launch_bounds__(128) void k_gnn(const float* __restrict__ wv,
                                             const int* __restrict__ wi,
                                             const long long* __restrict__ labels,
                                             const float* __restrict__ hin,
                                             const float* __restrict__ Wm,
                                             float* __restrict__ hout) {
    int row = blockIdx.x;
    int c = threadIdx.x;
    __shared__ float agg[NCLS];
    __shared__ float red[128];
    float a = 0.f;
    if (c < NCLS) {
        #pragma unroll
        for (int k = 0; k < KNB; ++k) {
            float wk = wv[(size_t)row * KNB + k];
            int id = wi[(size_t)row * KNB + k];
            if (FIRST) {
                if (id < QUEUE && labels[id] == (long long)c) a += wk;
            } else {
                a += wk * hin[(size_t)id * NCLS + c];
            }
        }
        agg[c] = a;
    }
    __syncthreads();
    float l = 0.f;
    if (c < NCLS) {
        for (int cc = 0; cc < NCLS; ++cc) l = fmaf(agg[cc], Wm[cc * NCLS + c], l);
    }
    red[threadIdx.x] = (c < NCLS) ? l : -1e30f;
    __syncthreads();
    for (int o = 64; o > 0; o >>= 1) {
        if (threadIdx.x < o) red[threadIdx.x] = fmaxf(red[threadIdx.x], red[threadIdx.x + o]);
        __syncthreads();
    }
    float m = red[0];
    __syncthreads();
    float e = (c < NCLS) ? expf(l - m) : 0.f;
    red[threadIdx.x] = e;
    __syncthreads();
    for (int o = 64; o > 0; o >>= 1) {
        if (threadIdx.x < o) red[threadIdx.x] += red[threadIdx.x + o];
        __syncthreads();
    }
    if (c < NCLS) hout[(size_t)row * NCLS + c] = e / red[0];
}

// ---------------- kernel 5: final pass (queries only) + confidence/argmax ----------------
__global__ __launch_bounds__(128) void k_final(const float* __restrict__ wv,
                                               const int* __restrict__ wi,
                                               const float* __restrict__ hin,
                                               const float* __restrict__ Wm,
                                               float* __restrict__ out) {
    int row = QUEUE + blockIdx.x;
    int c = threadIdx.x;
    __shared__ float agg[NCLS];
    __shared__ float redv[128];
    __shared__ int   redi[128];
    float a = 0.f;
    if (c < NCLS) {
        #pragma unroll
        for (int k = 0; k < KNB; ++k) {
            float wk = wv[(size_t)row * KNB + k];
            int id = wi[(size_t)row * KNB + k];
            a += wk * hin[(size_t)id * NCLS + c];
        }
        agg[c] = a;
    }
    __syncthreads();
    float l = -1e30f;
    if (c < NCLS) {
        l = 0.f;
        for (int cc = 0; cc < NCLS; ++cc) l = fmaf(agg[cc], Wm[cc * NCLS + c], l);
    }
    redv[threadIdx.x] = l;
    redi[threadIdx.x] = (c < NCLS) ? c : NCLS;
    __syncthreads();
    for (int o = 64; o > 0; o >>= 1) {
        if (threadIdx.x < o) {
            float v1 = redv[threadIdx.x], v2 = redv[threadIdx.x + o];
            int   i1 = redi[threadIdx.x], i2 = redi[threadIdx.x + o];
            if (v2 > v1 || (v2 == v1 && i2 < i1)) { redv[threadIdx.x] = v2; redi[threadIdx.x] = i2; }
        }
        __syncthreads();
    }
    float m = redv[0]; int pred = redi[0];
    __syncthreads();
    redv[threadIdx.x] = (c < NCLS) ? expf(l - m) : 0.f;
    __syncthreads();
    for (int o = 64; o > 0; o >>= 1) {
        if (threadIdx.x < o) redv[threadIdx.x] += redv[threadIdx.x + o];
        __syncthreads();
    }
    if (threadIdx.x == 0) {
        out[blockIdx.x]         = 1.0f / redv[0];   // confidence = max(softmax)
        out[BATCH + blockIdx.x] = (float)pred;      // predict
    }
}

// ---------------- host launcher ----------------
extern "C" void kernel_launch(void* const* d_in, const int* in_sizes, int n_in,
                              void* d_out, int out_size, void* d_ws, size_t ws_size,
                              hipStream_t stream) {
    const float*     x      = (const float*)d_in[0];      // (256,512)
    const float*     memory = (const float*)d_in[1];      // (8192,512)
    const float*     W      = (const float*)d_in[2];      // (65,65)
    const long long* labels = (const long long*)d_in[3];  // (8192,) int64

    float* sn  = (float*)d_ws;                            // NROW*DIM
    float* pwv = sn + (size_t)NROW * DIM;                 // NROW*NSPLIT*KNB
    int*   pwi = (int*)(pwv + (size_t)NROW * NSPLIT * KNB);
    float* wv  = (float*)(pwi + (size_t)NROW * NSPLIT * KNB);
    int*   wi  = (int*)(wv + (size_t)NROW * KNB);
    float* h0  = (float*)(wi + (size_t)NROW * KNB);
    float* h1  = h0 + (size_t)NROW * NCLS;

    k_norm<<<NROW, 128, 0, stream>>>(memory, x, sn);
    k_simtopk<<<(NROW / BM) * NSPLIT, 256, 0, stream>>>(sn, pwv, pwi);
    k_merge<<<(NROW + 255) / 256, 256, 0, stream>>>(pwv, pwi, wv, wi);
    k_gnn<1><<<NROW, 128, 0, stream>>>(wv, wi, labels, nullptr, W, h0);
    k_gnn<0><<<NROW, 128, 0, stream>>>(wv, wi, labels, h0, W, h1);
    k_final<<<BATCH, 128, 0, stream>>>(wv, wi, h1, W, (float*)d_out);
}

// Round 2
// 1467.448 us; speedup vs baseline: 1.6792x; 1.6792x over previous
//
#include <hip/hip_runtime.h>
#include <math.h>

#define QUEUE 8192
#define BATCH 256
#define NROW  8448        // QUEUE + BATCH
#define DIM   512
#define NCLS  65
#define KNB   10
#define NCAND 16          // rescored candidate set per row
#define NSPLIT 11
#define SPLITC 768        // 8448 / 11
#define BM 128
#define BN 128
#define BK 32
#define APAD 40           // padded LDS row stride in bf16 elems (80 B) -> conflict-free

typedef __attribute__((ext_vector_type(8))) short bf16x8;
typedef __attribute__((ext_vector_type(4))) float f32x4;

__device__ __forceinline__ unsigned short f2bf(float f) {
    unsigned int u = __float_as_uint(f);
    unsigned int r = (u + 0x7fffu + ((u >> 16) & 1u)) >> 16;   // RTNE
    return (unsigned short)r;
}

// ---------------- kernel 1: row normalize (fp32 + bf16 copies) ----------------
__global__ __launch_bounds__(128) void k_norm(const float* __restrict__ mem,
                                              const float* __restrict__ xq,
                                              float* __restrict__ sn,
                                              unsigned short* __restrict__ snb) {
    int row = blockIdx.x;
    const float* src = (row < QUEUE) ? (mem + (size_t)row * DIM)
                                     : (xq + (size_t)(row - QUEUE) * DIM);
    float4 v = reinterpret_cast<const float4*>(src)[threadIdx.x];
    float ss = v.x*v.x + v.y*v.y + v.z*v.z + v.w*v.w;
    #pragma unroll
    for (int o = 32; o > 0; o >>= 1) ss += __shfl_xor(ss, o);
    __shared__ float s2[2];
    if ((threadIdx.x & 63) == 0) s2[threadIdx.x >> 6] = ss;
    __syncthreads();
    float nrm = fmaxf(sqrtf(s2[0] + s2[1]), 1e-12f);
    float4 o4 = make_float4(v.x / nrm, v.y / nrm, v.z / nrm, v.w / nrm);
    reinterpret_cast<float4*>(sn + (size_t)row * DIM)[threadIdx.x] = o4;
    ushort4 b4;
    b4.x = f2bf(o4.x); b4.y = f2bf(o4.y); b4.z = f2bf(o4.z); b4.w = f2bf(o4.w);
    reinterpret_cast<ushort4*>(snb + (size_t)row * DIM)[threadIdx.x] = b4;
}

// ---------------- kernel 2: bf16 MFMA sim + fused per-row top-10 (per split) ----------------
// 4 waves; wave w owns rows [32w, 32w+32) of the 128-row band, full 128-col chunk.
__global__ __launch_bounds__(256) void k_simtopk(const unsigned short* __restrict__ snb,
                                                 float* __restrict__ pwv,
                                                 int* __restrict__ pwi) {
    __shared__ unsigned short Abuf[BM][APAD];
    __shared__ unsigned short Bbuf[BN][APAD];
    __shared__ float strip[4][8][132];       // per-wave 8-row x 128-col fp32 strip
    __shared__ float lv[BM][KNB];
    __shared__ int   li[BM][KNB];

    int band  = blockIdx.x / NSPLIT;
    int split = blockIdx.x % NSPLIT;
    int i0 = band * BM;
    int cbase = split * SPLITC;

    int tid  = threadIdx.x;
    int w    = tid >> 6;
    int lane = tid & 63;
    int lr   = lane & 15;
    int g    = lane >> 4;       // 0..3
    int lk8  = g * 8;           // k sub-chunk base

    for (int t = tid; t < BM * KNB; t += 256) {
        (&lv[0][0])[t] = -1e30f; (&li[0][0])[t] = 0;
    }
    __syncthreads();

    int srow = tid >> 1;             // staging row 0..127
    int sks  = (tid & 1) * 16;       // staging k-offset (bf16 elems)
    const unsigned short* ga = snb + (size_t)(i0 + srow) * DIM + sks;

    for (int chunk = 0; chunk < SPLITC / BN; ++chunk) {
        int c0 = cbase + chunk * BN;
        const unsigned short* gb = snb + (size_t)(c0 + srow) * DIM + sks;

        f32x4 acc[2][8];
        #pragma unroll
        for (int n = 0; n < 8; ++n) {
            acc[0][n] = (f32x4){0.f,0.f,0.f,0.f};
            acc[1][n] = (f32x4){0.f,0.f,0.f,0.f};
        }

        for (int k0 = 0; k0 < DIM; k0 += BK) {
            __syncthreads();   // everyone done with previous tile
            bf16x8 a0 = *reinterpret_cast<const bf16x8*>(ga + k0);
            bf16x8 a1 = *reinterpret_cast<const bf16x8*>(ga + k0 + 8);
            bf16x8 b0 = *reinterpret_cast<const bf16x8*>(gb + k0);
            bf16x8 b1 = *reinterpret_cast<const bf16x8*>(gb + k0 + 8);
            *reinterpret_cast<bf16x8*>(&Abuf[srow][sks])     = a0;
            *reinterpret_cast<bf16x8*>(&Abuf[srow][sks + 8]) = a1;
            *reinterpret_cast<bf16x8*>(&Bbuf[srow][sks])     = b0;
            *reinterpret_cast<bf16x8*>(&Bbuf[srow][sks + 8]) = b1;
            __syncthreads();

            bf16x8 af0 = *reinterpret_cast<const bf16x8*>(&Abuf[32*w      + lr][lk8]);
            bf16x8 af1 = *reinterpret_cast<const bf16x8*>(&Abuf[32*w + 16 + lr][lk8]);
            bf16x8 bfv[8];
            #pragma unroll
            for (int n = 0; n < 8; ++n)
                bfv[n] = *reinterpret_cast<const bf16x8*>(&Bbuf[16*n + lr][lk8]);
            #pragma unroll
            for (int n = 0; n < 8; ++n) {
                acc[0][n] = __builtin_amdgcn_mfma_f32_16x16x32_bf16(af0, bfv[n], acc[0][n], 0, 0, 0);
                acc[1][n] = __builtin_amdgcn_mfma_f32_16x16x32_bf16(af1, bfv[n], acc[1][n], 0, 0, 0);
            }
        }

        // selection: C layout col = lane&15, row = 4*(lane>>4)+j per 16x16 frag
        #pragma unroll
        for (int mp = 0; mp < 4; ++mp) {
            const int m = mp >> 1, p = mp & 1;
            __syncthreads();   // previous strip fully scanned
            #pragma unroll
            for (int n = 0; n < 8; ++n) {
                strip[w][2*g + 0][16*n + lr] = acc[m][n][2*p + 0];
                strip[w][2*g + 1][16*n + lr] = acc[m][n][2*p + 1];
            }
            __syncthreads();
            #pragma unroll 1
            for (int s = 0; s < 8; ++s) {
                int rloc = 32*w + 16*m + 4*(s >> 1) + 2*p + (s & 1);
                int grow = i0 + rloc;
                float v0 = strip[w][s][lane];
                float v1 = strip[w][s][64 + lane];
                float thr = lv[rloc][KNB - 1];
                unsigned long long m0 = __ballot((v0 > thr) && (c0 + lane != grow));
                unsigned long long m1 = __ballot((v1 > thr) && (c0 + 64 + lane != grow));
                while (m0 | m1) {
                    float cv; int cidx;
                    if (m0) { int l = __ffsll(m0) - 1; m0 &= m0 - 1; cv = __shfl(v0, l); cidx = c0 + l; }
                    else    { int l = __ffsll(m1) - 1; m1 &= m1 - 1; cv = __shfl(v1, l); cidx = c0 + 64 + l; }
                    thr = lv[rloc][KNB - 1];
                    if (cv > thr && lane == 0) {
                        int q = KNB - 1;
                        while (q > 0 && lv[rloc][q - 1] < cv) {
                            lv[rloc][q] = lv[rloc][q - 1];
                            li[rloc][q] = li[rloc][q - 1];
                            --q;
                        }
                        lv[rloc][q] = cv; li[rloc][q] = cidx;
                    }
                }
            }
        }
    }
    __syncthreads();
    for (int t = tid; t < BM * KNB; t += 256) {
        int r = t / KNB, q = t % KNB;
        size_t o = ((size_t)(i0 + r) * NSPLIT + split) * KNB + q;
        pwv[o] = lv[r][q]; pwi[o] = li[r][q];
    }
}

// ---------------- kernel 3: merge 11x10 bf16 partials -> top-16 candidate ids ----------------
__global__ __launch_bounds__(256) void k_merge16(const float* __restrict__ pwv,
                                                 const int* __restrict__ pwi,
                                                 int* __restrict__ ci) {
    int row = blockIdx.x * 256 + threadIdx.x;
    if (row >= NROW) return;
    float tv[NCAND]; int ti[NCAND];
    #pragma unroll
    for (int p = 0; p < NCAND; ++p) { tv[p] = -1e30f; ti[p] = 0; }
    const float* pv = pwv + (size_t)row * NSPLIT * KNB;
    const int*   pi = pwi + (size_t)row * NSPLIT * KNB;
    for (int s = 0; s < NSPLIT * KNB; ++s) {
        float v = pv[s]; int id = pi[s];
        #pragma unroll
        for (int p = NCAND - 1; p >= 1; --p) {
            bool shift = tv[p-1] < v;
            bool ins   = !shift && (tv[p] < v);
            tv[p] = shift ? tv[p-1] : (ins ? v  : tv[p]);
            ti[p] = shift ? ti[p-1] : (ins ? id : ti[p]);
        }
        if (tv[0] < v) { tv[0] = v; ti[0] = id; }
    }
    #pragma unroll
    for (int p = 0; p < NCAND; ++p) ci[(size_t)row * NCAND + p] = ti[p];
}

// ---------------- kernel 4: exact fp32 rescore of 16 candidates -> top-10 ----------------
__global__ __launch_bounds__(256) void k_rescore(const float* __restrict__ sn,
                                                 const int* __restrict__ ci,
                                                 float* __restrict__ wv,
                                                 int* __restrict__ wi) {
    int wq = threadIdx.x >> 6;
    int lane = threadIdx.x & 63;
    int row = blockIdx.x * 4 + wq;
    __shared__ float sd[4][NCAND];
    __shared__ int   sc[4][NCAND];
    const float4 q0 = *reinterpret_cast<const float4*>(sn + (size_t)row * DIM + 4 * lane);
    const float4 q1 = *reinterpret_cast<const float4*>(sn + (size_t)row * DIM + 256 + 4 * lane);
    for (int c = 0; c < NCAND; ++c) {
        int cid = ci[(size_t)row * NCAND + c];
        const float4 a = *reinterpret_cast<const float4*>(sn + (size_t)cid * DIM + 4 * lane);
        const float4 b = *reinterpret_cast<const float4*>(sn + (size_t)cid * DIM + 256 + 4 * lane);
        float d = q0.x*a.x + q0.y*a.y + q0.z*a.z + q0.w*a.w
                + q1.x*b.x + q1.y*b.y + q1.z*b.z + q1.w*b.w;
        #pragma unroll
        for (int o = 32; o > 0; o >>= 1) d += __shfl_xor(d, o);
        if (lane == 0) { sd[wq][c] = d; sc[wq][c] = cid; }
    }
    __syncthreads();
    if (lane < NCAND) {
        float d = sd[wq][lane];
        int myc = sc[wq][lane];
        int rank = 0;
        #pragma unroll
        for (int j = 0; j < NCAND; ++j) {
            float dj = sd[wq][j];
            int   cj = sc[wq][j];
            rank += (dj > d || (dj == d && cj < myc)) ? 1 : 0;
        }
        if (rank < KNB) {
            wv[(size_t)row * KNB + rank] = d;
            wi[(size_t)row * KNB + rank] = myc;
        }
    }
}

// ---------------- kernel 5: GNN pass (FIRST uses labels as implicit one-hot) ----------------
template<int FIRST>
__global__ __launch_bounds__(128) void k_gnn(const float* __restrict__ wv,
                                             const int* __restrict__ wi,
                                             const long long* __restrict__ labels,
                                             const float* __restrict__ hin,
                                             const float* __restrict__ Wm,
                                             float* __restrict__ hout) {
    int row = blockIdx.x;
    int c = threadIdx.x;
    __shared__ float agg[NCLS];
    __shared__ float red[128];
    float a = 0.f;
    if (c < NCLS) {
        #pragma unroll
        for (int k = 0; k < KNB; ++k) {
            float wk = wv[(size_t)row * KNB + k];
            int id = wi[(size_t)row * KNB + k];
            if (FIRST) {
                if (id < QUEUE && labels[id] == (long long)c) a += wk;
            } else {
                a += wk * hin[(size_t)id * NCLS + c];
            }
        }
        agg[c] = a;
    }
    __syncthreads();
    float l = 0.f;
    if (c < NCLS) {
        for (int cc = 0; cc < NCLS; ++cc) l = fmaf(agg[cc], Wm[cc * NCLS + c], l);
    }
    red[threadIdx.x] = (c < NCLS) ? l : -1e30f;
    __syncthreads();
    for (int o = 64; o > 0; o >>= 1) {
        if (threadIdx.x < o) red[threadIdx.x] = fmaxf(red[threadIdx.x], red[threadIdx.x + o]);
        __syncthreads();
    }
    float m = red[0];
    __syncthreads();
    float e = (c < NCLS) ? expf(l - m) : 0.f;
    red[threadIdx.x] = e;
    __syncthreads();
    for (int o = 64; o > 0; o >>= 1) {
        if (threadIdx.x < o) red[threadIdx.x] += red[threadIdx.x + o];
        __syncthreads();
    }
    if (c < NCLS) hout[(size_t)row * NCLS + c] = e / red[0];
}

// ---------------- kernel 6: final pass (queries) + confidence/argmax ----------------
__global__ __launch_bounds__(128) void k_final(const float* __restrict__ wv,
                                               const int* __restrict__ wi,
                                               const float* __restrict__ hin,
                                               const float* __restrict__ Wm,
                                               float* __restrict__ out) {
    int row = QUEUE + blockIdx.x;
    int c = threadIdx.x;
    __shared__ float agg[NCLS];
    __shared__ float redv[128];
    __shared__ int   redi[128];
    float a = 0.f;
    if (c < NCLS) {
        #pragma unroll
        for (int k = 0; k < KNB; ++k) {
            float wk = wv[(size_t)row * KNB + k];
            int id = wi[(size_t)row * KNB + k];
            a += wk * hin[(size_t)id * NCLS + c];
        }
        agg[c] = a;
    }
    __syncthreads();
    float l = -1e30f;
    if (c < NCLS) {
        l = 0.f;
        for (int cc = 0; cc < NCLS; ++cc) l = fmaf(agg[cc], Wm[cc * NCLS + c], l);
    }
    redv[threadIdx.x] = l;
    redi[threadIdx.x] = (c < NCLS) ? c : NCLS;
    __syncthreads();
    for (int o = 64; o > 0; o >>= 1) {
        if (threadIdx.x < o) {
            float v1 = redv[threadIdx.x], v2 = redv[threadIdx.x + o];
            int   i1 = redi[threadIdx.x], i2 = redi[threadIdx.x + o];
            if (v2 > v1 || (v2 == v1 && i2 < i1)) { redv[threadIdx.x] = v2; redi[threadIdx.x] = i2; }
        }
        __syncthreads();
    }
    float m = redv[0]; int pred = redi[0];
    __syncthreads();
    redv[threadIdx.x] = (c < NCLS) ? expf(l - m) : 0.f;
    __syncthreads();
    for (int o = 64; o > 0; o >>= 1) {
        if (threadIdx.x < o) redv[threadIdx.x] += redv[threadIdx.x + o];
        __syncthreads();
    }
    if (threadIdx.x == 0) {
        out[blockIdx.x]         = 1.0f / redv[0];
        out[BATCH + blockIdx.x] = (float)pred;
    }
}

// ---------------- host launcher ----------------
extern "C" void kernel_launch(void* const* d_in, const int* in_sizes, int n_in,
                              void* d_out, int out_size, void* d_ws, size_t ws_size,
                              hipStream_t stream) {
    const float*     x      = (const float*)d_in[0];      // (256,512)
    const float*     memory = (const float*)d_in[1];      // (8192,512)
    const float*     W      = (const float*)d_in[2];      // (65,65)
    const long long* labels = (const long long*)d_in[3];  // (8192,)

    float*          sn  = (float*)d_ws;                                    // NROW*DIM f32
    unsigned short* snb = (unsigned short*)(sn + (size_t)NROW * DIM);      // NROW*DIM bf16
    float* pwv = (float*)(snb + (size_t)NROW * DIM);                       // NROW*NSPLIT*KNB
    int*   pwi = (int*)(pwv + (size_t)NROW * NSPLIT * KNB);
    int*   ci  = (int*)(pwi + (size_t)NROW * NSPLIT * KNB);                // NROW*NCAND
    float* wv  = (float*)(ci + (size_t)NROW * NCAND);                      // NROW*KNB
    int*   wi  = (int*)(wv + (size_t)NROW * KNB);
    float* h0  = (float*)(wi + (size_t)NROW * KNB);                        // NROW*NCLS
    float* h1  = h0 + (size_t)NROW * NCLS;

    k_norm<<<NROW, 128, 0, stream>>>(memory, x, sn, snb);
    k_simtopk<<<(NROW / BM) * NSPLIT, 256, 0, stream>>>(snb, pwv, pwi);
    k_merge16<<<(NROW + 255) / 256, 256, 0, stream>>>(pwv, pwi, ci);
    k_rescore<<<NROW / 4, 256, 0, stream>>>(sn, ci, wv, wi);
    k_gnn<1><<<NROW, 128, 0, stream>>>(wv, wi, labels, nullptr, W, h0);
    k_gnn<0><<<NROW, 128, 0, stream>>>(wv, wi, labels, h0, W, h1);
    k_final<<<BATCH, 128, 0, stream>>>(wv, wi, h1, W, (float*)d_out);
}

// Round 3
// 463.957 us; speedup vs baseline: 5.3113x; 3.1629x over previous
//
#include <hip/hip_runtime.h>
#include <math.h>

#define QUEUE 8192
#define BATCH 256
#define NROW  8448        // QUEUE + BATCH
#define DIM   512
#define NCLS  65
#define KNB   10
#define NCAND 16          // rescored candidate set per row
#define NSPLIT 11
#define SPLITC 768        // 8448 / 11
#define BM 128
#define BN 128
#define BK 32
#define APAD 40           // padded LDS row stride in bf16 elems (80 B)
#define SP 132            // strip stride in floats: writes 2-way, float4 reads 2-way

typedef __attribute__((ext_vector_type(8))) short bf16x8;
typedef __attribute__((ext_vector_type(4))) float f32x4;

__device__ __forceinline__ unsigned short f2bf(float f) {
    unsigned int u = __float_as_uint(f);
    unsigned int r = (u + 0x7fffu + ((u >> 16) & 1u)) >> 16;   // RTNE
    return (unsigned short)r;
}

// ---------------- kernel 1: row normalize (fp32 + bf16 copies) ----------------
__global__ __launch_bounds__(128) void k_norm(const float* __restrict__ mem,
                                              const float* __restrict__ xq,
                                              float* __restrict__ sn,
                                              unsigned short* __restrict__ snb) {
    int row = blockIdx.x;
    const float* src = (row < QUEUE) ? (mem + (size_t)row * DIM)
                                     : (xq + (size_t)(row - QUEUE) * DIM);
    float4 v = reinterpret_cast<const float4*>(src)[threadIdx.x];
    float ss = v.x*v.x + v.y*v.y + v.z*v.z + v.w*v.w;
    #pragma unroll
    for (int o = 32; o > 0; o >>= 1) ss += __shfl_xor(ss, o);
    __shared__ float s2[2];
    if ((threadIdx.x & 63) == 0) s2[threadIdx.x >> 6] = ss;
    __syncthreads();
    float nrm = fmaxf(sqrtf(s2[0] + s2[1]), 1e-12f);
    float4 o4 = make_float4(v.x / nrm, v.y / nrm, v.z / nrm, v.w / nrm);
    reinterpret_cast<float4*>(sn + (size_t)row * DIM)[threadIdx.x] = o4;
    ushort4 b4;
    b4.x = f2bf(o4.x); b4.y = f2bf(o4.y); b4.z = f2bf(o4.z); b4.w = f2bf(o4.w);
    reinterpret_cast<ushort4*>(snb + (size_t)row * DIM)[threadIdx.x] = b4;
}

// insert v (with id gc) into descending register list tv/ti (compile-time indexed)
#define INS10(tv, ti, v, gc)                                        \
    do {                                                            \
        _Pragma("unroll")                                           \
        for (int p = KNB - 1; p >= 1; --p) {                        \
            bool sh  = tv[p-1] < (v);                               \
            bool ins = !sh && (tv[p] < (v));                        \
            tv[p] = sh ? tv[p-1] : (ins ? (v)  : tv[p]);            \
            ti[p] = sh ? ti[p-1] : (ins ? (gc) : ti[p]);            \
        }                                                           \
        if (tv[0] < (v)) { tv[0] = (v); ti[0] = (gc); }             \
    } while (0)

// ---------------- kernel 2: bf16 MFMA sim + register-private top-10 (per split) ----------------
// 4 waves; wave w owns rows [32w, 32w+32). Lane l scans strip row l>>2, cols 32*(l&3)..+31.
__global__ __launch_bounds__(256) void k_simtopk(const unsigned short* __restrict__ snb,
                                                 float* __restrict__ pwv,
                                                 int* __restrict__ pwi) {
    __shared__ unsigned short Abuf[BM][APAD];
    __shared__ unsigned short Bbuf[BN][APAD];
    __shared__ float strip[4][16][SP];      // per-wave 16-row x 128-col fp32 strip

    int band  = blockIdx.x / NSPLIT;
    int split = blockIdx.x % NSPLIT;
    int i0 = band * BM;
    int cbase = split * SPLITC;

    int tid  = threadIdx.x;
    int w    = tid >> 6;
    int lane = tid & 63;
    int lr   = lane & 15;
    int g    = lane >> 4;       // 0..3
    int lk8  = g * 8;           // k sub-chunk base (bf16 elems)

    int sq = lane >> 2;         // scan row within strip (0..15)
    int sc = lane & 3;          // scan col block (0..3) -> cols 32*sc..+31

    // lane-private top-10 lists (descending), one per m-half
    float tv0[KNB], tv1[KNB]; int ti0[KNB], ti1[KNB];
    #pragma unroll
    for (int p = 0; p < KNB; ++p) {
        tv0[p] = -1e30f; tv1[p] = -1e30f; ti0[p] = 0; ti1[p] = 0;
    }
    int grow0 = i0 + 32*w + sq;       // global row for m=0 list
    int grow1 = grow0 + 16;           // global row for m=1 list

    int srow = tid >> 1;              // staging row 0..127
    int sks  = (tid & 1) * 16;        // staging k-offset (bf16 elems)
    const unsigned short* ga = snb + (size_t)(i0 + srow) * DIM + sks;

    for (int chunk = 0; chunk < SPLITC / BN; ++chunk) {
        int c0 = cbase + chunk * BN;
        const unsigned short* gb = snb + (size_t)(c0 + srow) * DIM + sks;

        f32x4 acc[2][8];
        #pragma unroll
        for (int n = 0; n < 8; ++n) {
            acc[0][n] = (f32x4){0.f,0.f,0.f,0.f};
            acc[1][n] = (f32x4){0.f,0.f,0.f,0.f};
        }

        for (int k0 = 0; k0 < DIM; k0 += BK) {
            __syncthreads();   // all waves done reading previous tile
            bf16x8 a0 = *reinterpret_cast<const bf16x8*>(ga + k0);
            bf16x8 a1 = *reinterpret_cast<const bf16x8*>(ga + k0 + 8);
            bf16x8 b0 = *reinterpret_cast<const bf16x8*>(gb + k0);
            bf16x8 b1 = *reinterpret_cast<const bf16x8*>(gb + k0 + 8);
            *reinterpret_cast<bf16x8*>(&Abuf[srow][sks])     = a0;
            *reinterpret_cast<bf16x8*>(&Abuf[srow][sks + 8]) = a1;
            *reinterpret_cast<bf16x8*>(&Bbuf[srow][sks])     = b0;
            *reinterpret_cast<bf16x8*>(&Bbuf[srow][sks + 8]) = b1;
            __syncthreads();

            bf16x8 af0 = *reinterpret_cast<const bf16x8*>(&Abuf[32*w      + lr][lk8]);
            bf16x8 af1 = *reinterpret_cast<const bf16x8*>(&Abuf[32*w + 16 + lr][lk8]);
            bf16x8 bfv[8];
            #pragma unroll
            for (int n = 0; n < 8; ++n)
                bfv[n] = *reinterpret_cast<const bf16x8*>(&Bbuf[16*n + lr][lk8]);
            #pragma unroll
            for (int n = 0; n < 8; ++n) {
                acc[0][n] = __builtin_amdgcn_mfma_f32_16x16x32_bf16(af0, bfv[n], acc[0][n], 0, 0, 0);
                acc[1][n] = __builtin_amdgcn_mfma_f32_16x16x32_bf16(af1, bfv[n], acc[1][n], 0, 0, 0);
            }
        }

        // ---- per-wave strip + register-private selection (no cross-wave sync) ----
        // m = 0 half: rows 32w..32w+15
        #pragma unroll
        for (int n = 0; n < 8; ++n) {
            #pragma unroll
            for (int j = 0; j < 4; ++j)
                strip[w][4*g + j][16*n + lr] = acc[0][n][j];
        }
        #pragma unroll 1
        for (int ib = 0; ib < 8; ++ib) {
            f32x4 v4 = *reinterpret_cast<const f32x4*>(&strip[w][sq][32*sc + 4*ib]);
            float m4 = fmaxf(fmaxf(v4[0], v4[1]), fmaxf(v4[2], v4[3]));
            if (m4 > tv0[KNB-1]) {
                int gcb = c0 + 32*sc + 4*ib;
                #pragma unroll
                for (int e = 0; e < 4; ++e) {
                    float v = v4[e]; int gc = gcb + e;
                    if (v > tv0[KNB-1] && gc != grow0) INS10(tv0, ti0, v, gc);
                }
            }
        }
        // m = 1 half: rows 32w+16..32w+31 (reuse same strip; intra-wave order)
        #pragma unroll
        for (int n = 0; n < 8; ++n) {
            #pragma unroll
            for (int j = 0; j < 4; ++j)
                strip[w][4*g + j][16*n + lr] = acc[1][n][j];
        }
        #pragma unroll 1
        for (int ib = 0; ib < 8; ++ib) {
            f32x4 v4 = *reinterpret_cast<const f32x4*>(&strip[w][sq][32*sc + 4*ib]);
            float m4 = fmaxf(fmaxf(v4[0], v4[1]), fmaxf(v4[2], v4[3]));
            if (m4 > tv1[KNB-1]) {
                int gcb = c0 + 32*sc + 4*ib;
                #pragma unroll
                for (int e = 0; e < 4; ++e) {
                    float v = v4[e]; int gc = gcb + e;
                    if (v > tv1[KNB-1] && gc != grow1) INS10(tv1, ti1, v, gc);
                }
            }
        }
    }

    // ---- merge 4 lane-lists per row via shfl (leader = lane with sc==0) ----
    int src0 = lane & 60;
    #pragma unroll 1
    for (int src = 1; src <= 3; ++src) {
        #pragma unroll
        for (int p = 0; p < KNB; ++p) {
            float v0 = __shfl(tv0[p], src0 + src);
            int   c0i = __shfl(ti0[p], src0 + src);
            float v1 = __shfl(tv1[p], src0 + src);
            int   c1i = __shfl(ti1[p], src0 + src);
            if (sc == 0) {
                if (v0 > tv0[KNB-1]) INS10(tv0, ti0, v0, c0i);
                if (v1 > tv1[KNB-1]) INS10(tv1, ti1, v1, c1i);
            }
        }
    }
    if (sc == 0) {
        size_t b0 = ((size_t)grow0 * NSPLIT + split) * KNB;
        size_t b1 = ((size_t)grow1 * NSPLIT + split) * KNB;
        #pragma unroll
        for (int p = 0; p < KNB; ++p) {
            pwv[b0 + p] = tv0[p]; pwi[b0 + p] = ti0[p];
            pwv[b1 + p] = tv1[p]; pwi[b1 + p] = ti1[p];
        }
    }
}

// ---------------- kernel 3: merge 11x10 bf16 partials -> top-16 candidate ids ----------------
__global__ __launch_bounds__(256) void k_merge16(const float* __restrict__ pwv,
                                                 const int* __restrict__ pwi,
                                                 int* __restrict__ ci) {
    int row = blockIdx.x * 256 + threadIdx.x;
    if (row >= NROW) return;
    float tv[NCAND]; int ti[NCAND];
    #pragma unroll
    for (int p = 0; p < NCAND; ++p) { tv[p] = -1e30f; ti[p] = 0; }
    const float* pv = pwv + (size_t)row * NSPLIT * KNB;
    const int*   pi = pwi + (size_t)row * NSPLIT * KNB;
    for (int s = 0; s < NSPLIT * KNB; ++s) {
        float v = pv[s]; int id = pi[s];
        #pragma unroll
        for (int p = NCAND - 1; p >= 1; --p) {
            bool shift = tv[p-1] < v;
            bool ins   = !shift && (tv[p] < v);
            tv[p] = shift ? tv[p-1] : (ins ? v  : tv[p]);
            ti[p] = shift ? ti[p-1] : (ins ? id : ti[p]);
        }
        if (tv[0] < v) { tv[0] = v; ti[0] = id; }
    }
    #pragma unroll
    for (int p = 0; p < NCAND; ++p) ci[(size_t)row * NCAND + p] = ti[p];
}

// ---------------- kernel 4: exact fp32 rescore of 16 candidates -> top-10 ----------------
__global__ __launch_bounds__(256) void k_rescore(const float* __restrict__ sn,
                                                 const int* __restrict__ ci,
                                                 float* __restrict__ wv,
                                                 int* __restrict__ wi) {
    int wq = threadIdx.x >> 6;
    int lane = threadIdx.x & 63;
    int row = blockIdx.x * 4 + wq;
    __shared__ float sd[4][NCAND];
    __shared__ int   sc[4][NCAND];
    const float4 q0 = *reinterpret_cast<const float4*>(sn + (size_t)row * DIM + 4 * lane);
    const float4 q1 = *reinterpret_cast<const float4*>(sn + (size_t)row * DIM + 256 + 4 * lane);
    for (int c = 0; c < NCAND; ++c) {
        int cid = ci[(size_t)row * NCAND + c];
        const float4 a = *reinterpret_cast<const float4*>(sn + (size_t)cid * DIM + 4 * lane);
        const float4 b = *reinterpret_cast<const float4*>(sn + (size_t)cid * DIM + 256 + 4 * lane);
        float d = q0.x*a.x + q0.y*a.y + q0.z*a.z + q0.w*a.w
                + q1.x*b.x + q1.y*b.y + q1.z*b.z + q1.w*b.w;
        #pragma unroll
        for (int o = 32; o > 0; o >>= 1) d += __shfl_xor(d, o);
        if (lane == 0) { sd[wq][c] = d; sc[wq][c] = cid; }
    }
    __syncthreads();
    if (lane < NCAND) {
        float d = sd[wq][lane];
        int myc = sc[wq][lane];
        int rank = 0;
        #pragma unroll
        for (int j = 0; j < NCAND; ++j) {
            float dj = sd[wq][j];
            int   cj = sc[wq][j];
            rank += (dj > d || (dj == d && cj < myc)) ? 1 : 0;
        }
        if (rank < KNB) {
            wv[(size_t)row * KNB + rank] = d;
            wi[(size_t)row * KNB + rank] = myc;
        }
    }
}

// ---------------- kernel 5: GNN pass (FIRST uses labels as implicit one-hot) ----------------
template<int FIRST>
__global__ __launch_bounds__(128) void k_gnn(const float* __restrict__ wv,
                                             const int* __restrict__ wi,
                                             const long long* __restrict__ labels,
                                             const float* __restrict__ hin,
                                             const float* __restrict__ Wm,
                                             float* __restrict__ hout) {
    int row = blockIdx.x;
    int c = threadIdx.x;
    __shared__ float agg[NCLS];
    __shared__ float red[128];
    float a = 0.f;
    if (c < NCLS) {
        #pragma unroll
        for (int k = 0; k < KNB; ++k) {
            float wk = wv[(size_t)row * KNB + k];
            int id = wi[(size_t)row * KNB + k];
            if (FIRST) {
                if (id < QUEUE && labels[id] == (long long)c) a += wk;
            } else {
                a += wk * hin[(size_t)id * NCLS + c];
            }
        }
        agg[c] = a;
    }
    __syncthreads();
    float l = 0.f;
    if (c < NCLS) {
        for (int cc = 0; cc < NCLS; ++cc) l = fmaf(agg[cc], Wm[cc * NCLS + c], l);
    }
    red[threadIdx.x] = (c < NCLS) ? l : -1e30f;
    __syncthreads();
    for (int o = 64; o > 0; o >>= 1) {
        if (threadIdx.x < o) red[threadIdx.x] = fmaxf(red[threadIdx.x], red[threadIdx.x + o]);
        __syncthreads();
    }
    float m = red[0];
    __syncthreads();
    float e = (c < NCLS) ? expf(l - m) : 0.f;
    red[threadIdx.x] = e;
    __syncthreads();
    for (int o = 64; o > 0; o >>= 1) {
        if (threadIdx.x < o) red[threadIdx.x] += red[threadIdx.x + o];
        __syncthreads();
    }
    if (c < NCLS) hout[(size_t)row * NCLS + c] = e / red[0];
}

// ---------------- kernel 6: final pass (queries) + confidence/argmax ----------------
__global__ __launch_bounds__(128) void k_final(const float* __restrict__ wv,
                                               const int* __restrict__ wi,
                                               const float* __restrict__ hin,
                                               const float* __restrict__ Wm,
                                               float* __restrict__ out) {
    int row = QUEUE + blockIdx.x;
    int c = threadIdx.x;
    __shared__ float agg[NCLS];
    __shared__ float redv[128];
    __shared__ int   redi[128];
    float a = 0.f;
    if (c < NCLS) {
        #pragma unroll
        for (int k = 0; k < KNB; ++k) {
            float wk = wv[(size_t)row * KNB + k];
            int id = wi[(size_t)row * KNB + k];
            a += wk * hin[(size_t)id * NCLS + c];
        }
        agg[c] = a;
    }
    __syncthreads();
    float l = -1e30f;
    if (c < NCLS) {
        l = 0.f;
        for (int cc = 0; cc < NCLS; ++cc) l = fmaf(agg[cc], Wm[cc * NCLS + c], l);
    }
    redv[threadIdx.x] = l;
    redi[threadIdx.x] = (c < NCLS) ? c : NCLS;
    __syncthreads();
    for (int o = 64; o > 0; o >>= 1) {
        if (threadIdx.x < o) {
            float v1 = redv[threadIdx.x], v2 = redv[threadIdx.x + o];
            int   i1 = redi[threadIdx.x], i2 = redi[threadIdx.x + o];
            if (v2 > v1 || (v2 == v1 && i2 < i1)) { redv[threadIdx.x] = v2; redi[threadIdx.x] = i2; }
        }
        __syncthreads();
    }
    float m = redv[0]; int pred = redi[0];
    __syncthreads();
    redv[threadIdx.x] = (c < NCLS) ? expf(l - m) : 0.f;
    __syncthreads();
    for (int o = 64; o > 0; o >>= 1) {
        if (threadIdx.x < o) redv[threadIdx.x] += redv[threadIdx.x + o];
        __syncthreads();
    }
    if (threadIdx.x == 0) {
        out[blockIdx.x]         = 1.0f / redv[0];
        out[BATCH + blockIdx.x] = (float)pred;
    }
}

// ---------------- host launcher ----------------
extern "C" void kernel_launch(void* const* d_in, const int* in_sizes, int n_in,
                              void* d_out, int out_size, void* d_ws, size_t ws_size,
                              hipStream_t stream) {
    const float*     x      = (const float*)d_in[0];      // (256,512)
    const float*     memory = (const float*)d_in[1];      // (8192,512)
    const float*     W      = (const float*)d_in[2];      // (65,65)
    const long long* labels = (const long long*)d_in[3];  // (8192,)

    float*          sn  = (float*)d_ws;                                    // NROW*DIM f32
    unsigned short* snb = (unsigned short*)(sn + (size_t)NROW * DIM);      // NROW*DIM bf16
    float* pwv = (float*)(snb + (size_t)NROW * DIM);                       // NROW*NSPLIT*KNB
    int*   pwi = (int*)(pwv + (size_t)NROW * NSPLIT * KNB);
    int*   ci  = (int*)(pwi + (size_t)NROW * NSPLIT * KNB);                // NROW*NCAND
    float* wv  = (float*)(ci + (size_t)NROW * NCAND);                      // NROW*KNB
    int*   wi  = (int*)(wv + (size_t)NROW * KNB);
    float* h0  = (float*)(wi + (size_t)NROW * KNB);                        // NROW*NCLS
    float* h1  = h0 + (size_t)NROW * NCLS;

    k_norm<<<NROW, 128, 0, stream>>>(memory, x, sn, snb);
    k_simtopk<<<(NROW / BM) * NSPLIT, 256, 0, stream>>>(snb, pwv, pwi);
    k_merge16<<<(NROW + 255) / 256, 256, 0, stream>>>(pwv, pwi, ci);
    k_rescore<<<NROW / 4, 256, 0, stream>>>(sn, ci, wv, wi);
    k_gnn<1><<<NROW, 128, 0, stream>>>(wv, wi, labels, nullptr, W, h0);
    k_gnn<0><<<NROW, 128, 0, stream>>>(wv, wi, labels, h0, W, h1);
    k_final<<<BATCH, 128, 0, stream>>>(wv, wi, h1, W, (float*)d_out);
}